// Round 3
// baseline (24538.966 us; speedup 1.0000x reference)
//
#include <hip/hip_runtime.h>
#include <math.h>

#define S_LEN 4096
#define HDIRC 256
#define NTAG 10
#define START_TAG 8
#define STOP_TAG 9
#define NEGV -10000.0f

// -------- workspace layout (float units) --------
#define XW_OFF 0UL
#define XW_SZ  (2UL * S_LEN * 1024)          // xw[dir][t][1024]
#define HS_OFF (XW_OFF + XW_SZ)
#define HS_SZ  (2UL * S_LEN * 256)           // hs[dir][t][256] (dir1 indexed by backward step)
#define WT_OFF (HS_OFF + HS_SZ)
#define WT_SZ  (2UL * 256 * 1024)            // WihT[dir][k][r]
#define FE_OFF (WT_OFF + WT_SZ)
#define FE_SZ  ((size_t)S_LEN * NTAG)        // feats[t][tag]
#define RING_OFF (FE_OFF + FE_SZ)            // even float offset -> 8B aligned
#define RING_SZ (2UL * 2 * 256 * 2)          // u64 ring[dir][slot][dim], as floats

// ---------------- Wih transpose: [1024][256] -> [256][1024] ----------------
__global__ void transpose_wih(const float* __restrict__ wf,
                              const float* __restrict__ wb,
                              float* __restrict__ wT) {
    __shared__ float tile[32][33];
    const float* src = blockIdx.z ? wb : wf;
    float* dst = wT + (size_t)blockIdx.z * 256 * 1024;
    int x = blockIdx.x * 32 + threadIdx.x;   // k  (0..255)
    int y = blockIdx.y * 32 + threadIdx.y;   // r  (0..1023)
    tile[threadIdx.y][threadIdx.x] = src[y * 256 + x];
    __syncthreads();
    int ko = blockIdx.x * 32 + threadIdx.y;
    int ro = blockIdx.y * 32 + threadIdx.x;
    dst[(size_t)ko * 1024 + ro] = tile[threadIdx.x][threadIdx.y];
}

// ---------------- xW = emb[sent] @ Wih^T + (bih+bhh) ----------------
__global__ __launch_bounds__(256) void xw_gemm(
    const int* __restrict__ sent, const float* __restrict__ emb,
    const float* __restrict__ wT,
    const float* __restrict__ bih_f, const float* __restrict__ bhh_f,
    const float* __restrict__ bih_b, const float* __restrict__ bhh_b,
    float* __restrict__ xw) {
    int dir = blockIdx.y;
    int t0 = blockIdx.x * 16;
    int tid = threadIdx.x;
    __shared__ __align__(16) float xs[16][256];
    for (int i = 0; i < 16; ++i) {
        int t = t0 + i;
        int pos = dir ? (S_LEN - 1 - t) : t;
        int idx = sent[pos];
        xs[i][tid] = emb[(size_t)idx * 256 + tid];
    }
    __syncthreads();
    const float* w = wT + (size_t)dir * 256 * 1024;
    const float* bi = dir ? bih_b : bih_f;
    const float* bh = dir ? bhh_b : bhh_f;
    float4 bv;
    bv.x = bi[4 * tid + 0] + bh[4 * tid + 0];
    bv.y = bi[4 * tid + 1] + bh[4 * tid + 1];
    bv.z = bi[4 * tid + 2] + bh[4 * tid + 2];
    bv.w = bi[4 * tid + 3] + bh[4 * tid + 3];
    float4 acc[16];
#pragma unroll
    for (int i = 0; i < 16; ++i) acc[i] = bv;
    for (int k4 = 0; k4 < 64; ++k4) {
        float4 w0 = ((const float4*)(w + (size_t)(4 * k4 + 0) * 1024))[tid];
        float4 w1 = ((const float4*)(w + (size_t)(4 * k4 + 1) * 1024))[tid];
        float4 w2 = ((const float4*)(w + (size_t)(4 * k4 + 2) * 1024))[tid];
        float4 w3 = ((const float4*)(w + (size_t)(4 * k4 + 3) * 1024))[tid];
#pragma unroll
        for (int i = 0; i < 16; ++i) {
            float4 xv = *(const float4*)&xs[i][4 * k4];
            acc[i].x = fmaf(w0.x, xv.x, acc[i].x);
            acc[i].y = fmaf(w0.y, xv.x, acc[i].y);
            acc[i].z = fmaf(w0.z, xv.x, acc[i].z);
            acc[i].w = fmaf(w0.w, xv.x, acc[i].w);
            acc[i].x = fmaf(w1.x, xv.y, acc[i].x);
            acc[i].y = fmaf(w1.y, xv.y, acc[i].y);
            acc[i].z = fmaf(w1.z, xv.y, acc[i].z);
            acc[i].w = fmaf(w1.w, xv.y, acc[i].w);
            acc[i].x = fmaf(w2.x, xv.z, acc[i].x);
            acc[i].y = fmaf(w2.y, xv.z, acc[i].y);
            acc[i].z = fmaf(w2.z, xv.z, acc[i].z);
            acc[i].w = fmaf(w2.w, xv.z, acc[i].w);
            acc[i].x = fmaf(w3.x, xv.w, acc[i].x);
            acc[i].y = fmaf(w3.y, xv.w, acc[i].y);
            acc[i].z = fmaf(w3.z, xv.w, acc[i].z);
            acc[i].w = fmaf(w3.w, xv.w, acc[i].w);
        }
    }
#pragma unroll
    for (int i = 0; i < 16; ++i)
        ((float4*)(xw + ((size_t)dir * S_LEN + t0 + i) * 1024))[tid] = acc[i];
}

// ---------------- LSTM recurrence ----------------
// 32 blocks x 256 threads. blk -> (dir = blk>>4, b = blk&15). Block owns
// h-dims [16b,16b+16) => 64 rows (4 gates x 16 dims). Thread (g=tid>>6,
// s=(tid&63)>>2, q=tid&3) holds Whh[g*256+16b+s][64q..64q+63] = 64 floats in
// VGPRs (fits: ~110 VGPR total, no spill, unlike 256/thread in R1/R2).
// Gate activations computed per-wave (4 SIMDs in parallel); wave0 publishes
// 16 stamped {t+1,h} 8B pairs to an IC ring and polls all 256 dims.
__global__ __launch_bounds__(256, 1) void lstm_rec(
    const float* __restrict__ whh_f, const float* __restrict__ whh_b,
    const float* __restrict__ xw, float* __restrict__ hs,
    unsigned long long* __restrict__ ring) {
    int blk = blockIdx.x;
    int dir = blk >> 4;
    int b = blk & 15;
    int tid = threadIdx.x;
    int g = tid >> 6;          // gate / wave
    int lane = tid & 63;
    int s = lane >> 2;         // local dim 0..15
    int q = lane & 3;          // k-chunk 0..3
    int row = g * 256 + b * 16 + s;

    const float* whh = dir ? whh_b : whh_f;
    const float4* wrow = (const float4*)(whh + (size_t)row * 256 + q * 64);
    float4 w[16];
#pragma unroll
    for (int i = 0; i < 16; ++i) w[i] = wrow[i];
#pragma unroll
    for (int i = 0; i < 16; ++i)
        asm volatile("" : "+v"(w[i].x), "+v"(w[i].y), "+v"(w[i].z), "+v"(w[i].w));

    const float* xwd = xw + (size_t)dir * S_LEN * 1024;
    float* hsd = hs + (size_t)dir * S_LEN * 256;
    unsigned long long* ringd = ring + dir * 512;   // [slot(2)][dim(256)]

    __shared__ __align__(16) float hbf[256];   // h_{t-1}
    __shared__ __align__(16) float zpart[256]; // partials [g][s][q]
    __shared__ float actb[64];                 // activations [g][16]
    hbf[tid] = 0.f;
    float c = 0.f;                             // cell state (wave0 lanes<16)
    int crow = g * 256 + b * 16 + lane;        // combiner row (lane<16)
    float xw_cur = (lane < 16) ? xwd[crow] : 0.f;
    __syncthreads();

    for (int t = 0; t < S_LEN; ++t) {
        // partial matvec over k in [64q, 64q+64); read order rotated by q so
        // the 4 distinct b128 addrs land 2-way per bank (free, m136)
        const float4* hb4 = (const float4*)hbf;
        float4 a = make_float4(0.f, 0.f, 0.f, 0.f);
#pragma unroll
        for (int i = 0; i < 16; ++i) {
            int m = (i + 4 * q) & 15;
            float4 h4 = hb4[q * 16 + m];
            float4 wm = w[m];
            a.x = fmaf(wm.x, h4.x, a.x);
            a.y = fmaf(wm.y, h4.y, a.y);
            a.z = fmaf(wm.z, h4.z, a.z);
            a.w = fmaf(wm.w, h4.w, a.w);
        }
        zpart[tid] = (a.x + a.y) + (a.z + a.w);
        __syncthreads();   // (A) zpart ready

        // combine + activation: lanes<16 of each wave handle this wave's gate
        if (lane < 16) {
            float4 zp = *(const float4*)&zpart[g * 64 + lane * 4];
            float z = xw_cur + ((zp.x + zp.y) + (zp.z + zp.w));
            float xw_next = (t + 1 < S_LEN) ? xwd[(size_t)(t + 1) * 1024 + crow] : 0.f;
            float act = (g == 2) ? tanhf(z) : 1.f / (1.f + expf(-z));
            actb[g * 16 + lane] = act;
            xw_cur = xw_next;
        }
        __syncthreads();   // (B) actb ready

        unsigned long long* slot = ringd + (size_t)(t & 1) * 256;
        unsigned int want = (unsigned int)(t + 1);
        if (g == 0) {
            if (lane < 16) {
                float ig = actb[lane], fg = actb[16 + lane];
                float gg = actb[32 + lane], og = actb[48 + lane];
                c = fmaf(fg, c, ig * gg);
                float h = og * tanhf(c);
                hsd[(size_t)t * 256 + b * 16 + lane] = h;
                unsigned long long pk = ((unsigned long long)want << 32) |
                                        (unsigned long long)__float_as_uint(h);
                __hip_atomic_store(&slot[b * 16 + lane], pk,
                                   __ATOMIC_RELAXED, __HIP_MEMORY_SCOPE_AGENT);
            }
            unsigned long long v0, v1, v2, v3;
            for (;;) {
                v0 = __hip_atomic_load(&slot[lane], __ATOMIC_RELAXED, __HIP_MEMORY_SCOPE_AGENT);
                v1 = __hip_atomic_load(&slot[lane + 64], __ATOMIC_RELAXED, __HIP_MEMORY_SCOPE_AGENT);
                v2 = __hip_atomic_load(&slot[lane + 128], __ATOMIC_RELAXED, __HIP_MEMORY_SCOPE_AGENT);
                v3 = __hip_atomic_load(&slot[lane + 192], __ATOMIC_RELAXED, __HIP_MEMORY_SCOPE_AGENT);
                bool ok = ((unsigned int)(v0 >> 32) == want) &
                          ((unsigned int)(v1 >> 32) == want) &
                          ((unsigned int)(v2 >> 32) == want) &
                          ((unsigned int)(v3 >> 32) == want);
                if (__all(ok)) break;
            }
            hbf[lane]       = __uint_as_float((unsigned int)v0);
            hbf[lane + 64]  = __uint_as_float((unsigned int)v1);
            hbf[lane + 128] = __uint_as_float((unsigned int)v2);
            hbf[lane + 192] = __uint_as_float((unsigned int)v3);
        }
        __syncthreads();   // (C) hbf = h_t for everyone
    }
}

// ---------------- feats = [h_f, h_b] @ W_out^T + b_out ----------------
__global__ __launch_bounds__(64) void feats_k(const float* __restrict__ hs,
                                              const float* __restrict__ wout,
                                              const float* __restrict__ bout,
                                              float* __restrict__ feats) {
    int t = blockIdx.x, tau = blockIdx.y, lane = threadIdx.x;
    const float* hf = hs + (size_t)t * 256;
    const float* hbk = hs + (size_t)S_LEN * 256 + (size_t)(S_LEN - 1 - t) * 256;
    const float* w = wout + (size_t)tau * 512;
    float s = 0.f;
#pragma unroll
    for (int m = 0; m < 4; ++m) s = fmaf(w[lane + 64 * m], hf[lane + 64 * m], s);
#pragma unroll
    for (int m = 0; m < 4; ++m) s = fmaf(w[256 + lane + 64 * m], hbk[lane + 64 * m], s);
#pragma unroll
    for (int off = 32; off > 0; off >>= 1) s += __shfl_down(s, off, 64);
    if (lane == 0) feats[(size_t)t * NTAG + tau] = s + bout[tau];
}

// ---------------- Viterbi (single wave; bp table + path in LDS) ----------------
__global__ __launch_bounds__(64) void viterbi_k(const float* __restrict__ feats,
                                                const float* __restrict__ trans,
                                                float* __restrict__ out) {
    __shared__ float fstage[128 * NTAG];
    __shared__ unsigned char bp[S_LEN * NTAG];
    __shared__ float path[S_LEN];
    __shared__ float fvbuf[NTAG];
    __shared__ float term[NTAG];
    int tid = threadIdx.x;
    float tr[NTAG];
    float trstop = 0.f;
    if (tid < NTAG) {
#pragma unroll
        for (int j = 0; j < NTAG; ++j) tr[j] = trans[tid * NTAG + j];
        trstop = trans[STOP_TAG * NTAG + tid];
    }
    float fv = (tid == START_TAG) ? 0.f : NEGV;
    for (int t0 = 0; t0 < S_LEN; t0 += 128) {
        __syncthreads();
        for (int i = tid; i < 128 * NTAG; i += 64) fstage[i] = feats[(size_t)t0 * NTAG + i];
        __syncthreads();
        for (int tt = 0; tt < 128; ++tt) {
            int t = t0 + tt;
            if (tid < NTAG) fvbuf[tid] = fv;
            __syncthreads();
            if (tid < NTAG) {
                float best = -3.4e38f; int bj = 0;
#pragma unroll
                for (int j = 0; j < NTAG; ++j) {
                    float v = fvbuf[j] + tr[j];
                    if (v > best) { best = v; bj = j; }
                }
                bp[t * NTAG + tid] = (unsigned char)bj;
                fv = best + fstage[tt * NTAG + tid];
            }
            __syncthreads();
        }
    }
    if (tid < NTAG) term[tid] = fv + trstop;
    __syncthreads();
    if (tid == 0) {
        float best = -3.4e38f; int bi = 0;
#pragma unroll
        for (int i = 0; i < NTAG; ++i) {
            float v = term[i];
            if (v > best) { best = v; bi = i; }
        }
        out[0] = best;
        int tag = bi;
        for (int t = S_LEN - 1; t >= 0; --t) {
            path[t] = (float)tag;
            tag = bp[t * NTAG + tag];
        }
    }
    __syncthreads();
    for (int i = tid; i < S_LEN; i += 64) out[1 + i] = path[i];
}

extern "C" void kernel_launch(void* const* d_in, const int* in_sizes, int n_in,
                              void* d_out, int out_size, void* d_ws, size_t ws_size,
                              hipStream_t stream) {
    const int* sent = (const int*)d_in[0];
    const float* emb = (const float*)d_in[1];
    const float* wih_f = (const float*)d_in[2];
    const float* whh_f = (const float*)d_in[3];
    const float* bih_f = (const float*)d_in[4];
    const float* bhh_f = (const float*)d_in[5];
    const float* wih_b = (const float*)d_in[6];
    const float* whh_b = (const float*)d_in[7];
    const float* bih_b = (const float*)d_in[8];
    const float* bhh_b = (const float*)d_in[9];
    const float* wout = (const float*)d_in[10];
    const float* bout = (const float*)d_in[11];
    const float* trans = (const float*)d_in[12];

    float* ws = (float*)d_ws;
    float* xw = ws + XW_OFF;
    float* hs = ws + HS_OFF;
    float* wT = ws + WT_OFF;
    float* fe = ws + FE_OFF;
    unsigned long long* ring = (unsigned long long*)(ws + RING_OFF);

    hipLaunchKernelGGL(transpose_wih, dim3(8, 32, 2), dim3(32, 32), 0, stream,
                       wih_f, wih_b, wT);
    hipLaunchKernelGGL(xw_gemm, dim3(S_LEN / 16, 2), dim3(256), 0, stream,
                       sent, emb, wT, bih_f, bhh_f, bih_b, bhh_b, xw);
    hipLaunchKernelGGL(lstm_rec, dim3(32), dim3(256), 0, stream,
                       whh_f, whh_b, xw, hs, ring);
    hipLaunchKernelGGL(feats_k, dim3(S_LEN, NTAG), dim3(64), 0, stream,
                       hs, wout, bout, fe);
    hipLaunchKernelGGL(viterbi_k, dim3(1), dim3(64), 0, stream,
                       fe, trans, (float*)d_out);
}

// Round 4
// 7567.717 us; speedup vs baseline: 3.2426x; 3.2426x over previous
//
#include <hip/hip_runtime.h>
#include <math.h>

#define S_LEN 4096
#define HDIRC 256
#define NTAG 10
#define START_TAG 8
#define STOP_TAG 9
#define NEGV -10000.0f

// -------- workspace layout (float units) --------
#define XW_OFF 0UL
#define XW_SZ  (2UL * S_LEN * 1024)          // xw[dir][t][1024]
#define HS_OFF (XW_OFF + XW_SZ)
#define HS_SZ  (2UL * S_LEN * 256)           // hs[dir][t][256] (dir1 indexed by backward step)
#define WT_OFF (HS_OFF + HS_SZ)
#define WT_SZ  (2UL * 256 * 1024)            // WihT[dir][k][r]
#define FE_OFF (WT_OFF + WT_SZ)
#define FE_SZ  ((size_t)S_LEN * NTAG)        // feats[t][tag]
#define RING_OFF (FE_OFF + FE_SZ)            // even float offset -> 8B aligned
#define RING_SZ (2UL * 2 * 256 * 2)          // u64 ring[dir][slot][dim], as floats

// ---------------- Wih transpose: [1024][256] -> [256][1024] ----------------
__global__ void transpose_wih(const float* __restrict__ wf,
                              const float* __restrict__ wb,
                              float* __restrict__ wT) {
    __shared__ float tile[32][33];
    const float* src = blockIdx.z ? wb : wf;
    float* dst = wT + (size_t)blockIdx.z * 256 * 1024;
    int x = blockIdx.x * 32 + threadIdx.x;   // k  (0..255)
    int y = blockIdx.y * 32 + threadIdx.y;   // r  (0..1023)
    tile[threadIdx.y][threadIdx.x] = src[y * 256 + x];
    __syncthreads();
    int ko = blockIdx.x * 32 + threadIdx.y;
    int ro = blockIdx.y * 32 + threadIdx.x;
    dst[(size_t)ko * 1024 + ro] = tile[threadIdx.x][threadIdx.y];
}

// ---------------- xW = emb[sent] @ Wih^T + (bih+bhh) ----------------
__global__ __launch_bounds__(256) void xw_gemm(
    const int* __restrict__ sent, const float* __restrict__ emb,
    const float* __restrict__ wT,
    const float* __restrict__ bih_f, const float* __restrict__ bhh_f,
    const float* __restrict__ bih_b, const float* __restrict__ bhh_b,
    float* __restrict__ xw) {
    int dir = blockIdx.y;
    int t0 = blockIdx.x * 16;
    int tid = threadIdx.x;
    __shared__ __align__(16) float xs[16][256];
    for (int i = 0; i < 16; ++i) {
        int t = t0 + i;
        int pos = dir ? (S_LEN - 1 - t) : t;
        int idx = sent[pos];
        xs[i][tid] = emb[(size_t)idx * 256 + tid];
    }
    __syncthreads();
    const float* w = wT + (size_t)dir * 256 * 1024;
    const float* bi = dir ? bih_b : bih_f;
    const float* bh = dir ? bhh_b : bhh_f;
    float4 bv;
    bv.x = bi[4 * tid + 0] + bh[4 * tid + 0];
    bv.y = bi[4 * tid + 1] + bh[4 * tid + 1];
    bv.z = bi[4 * tid + 2] + bh[4 * tid + 2];
    bv.w = bi[4 * tid + 3] + bh[4 * tid + 3];
    float4 acc[16];
#pragma unroll
    for (int i = 0; i < 16; ++i) acc[i] = bv;
    for (int k4 = 0; k4 < 64; ++k4) {
        float4 w0 = ((const float4*)(w + (size_t)(4 * k4 + 0) * 1024))[tid];
        float4 w1 = ((const float4*)(w + (size_t)(4 * k4 + 1) * 1024))[tid];
        float4 w2 = ((const float4*)(w + (size_t)(4 * k4 + 2) * 1024))[tid];
        float4 w3 = ((const float4*)(w + (size_t)(4 * k4 + 3) * 1024))[tid];
#pragma unroll
        for (int i = 0; i < 16; ++i) {
            float4 xv = *(const float4*)&xs[i][4 * k4];
            acc[i].x = fmaf(w0.x, xv.x, acc[i].x);
            acc[i].y = fmaf(w0.y, xv.x, acc[i].y);
            acc[i].z = fmaf(w0.z, xv.x, acc[i].z);
            acc[i].w = fmaf(w0.w, xv.x, acc[i].w);
            acc[i].x = fmaf(w1.x, xv.y, acc[i].x);
            acc[i].y = fmaf(w1.y, xv.y, acc[i].y);
            acc[i].z = fmaf(w1.z, xv.y, acc[i].z);
            acc[i].w = fmaf(w1.w, xv.y, acc[i].w);
            acc[i].x = fmaf(w2.x, xv.z, acc[i].x);
            acc[i].y = fmaf(w2.y, xv.z, acc[i].y);
            acc[i].z = fmaf(w2.z, xv.z, acc[i].z);
            acc[i].w = fmaf(w2.w, xv.z, acc[i].w);
            acc[i].x = fmaf(w3.x, xv.w, acc[i].x);
            acc[i].y = fmaf(w3.y, xv.w, acc[i].y);
            acc[i].z = fmaf(w3.z, xv.w, acc[i].z);
            acc[i].w = fmaf(w3.w, xv.w, acc[i].w);
        }
    }
#pragma unroll
    for (int i = 0; i < 16; ++i)
        ((float4*)(xw + ((size_t)dir * S_LEN + t0 + i) * 1024))[tid] = acc[i];
}

// ---------------- LSTM recurrence ----------------
// 32 blocks x 256 threads. blk -> (dir = blk>>4, b = blk&15). Block owns
// h-dims [16b,16b+16) => 64 rows (4 gates x 16 dims). Thread (g=tid>>6,
// v=(tid&63)>>2, u=tid&3) holds Whh[g*256+16b+4u+j][16v..16v+15] for j=0..3
// = 64 floats, ALL STATICALLY INDEXED (R3's dynamic index forced scratch).
// Post-matvec work is done by wave0 alone: activation per lane (4 gates x 16
// dims), i/f/g/o gathered by __shfl (no LDS round trip), c/h in lanes<16,
// stamped {t+1,h} 8B publish to IC ring, poll, hbf write. 2 barriers/step.
__global__ __launch_bounds__(256, 1) void lstm_rec(
    const float* __restrict__ whh_f, const float* __restrict__ whh_b,
    const float* __restrict__ xw, float* __restrict__ hs,
    unsigned long long* __restrict__ ring) {
    int blk = blockIdx.x;
    int dir = blk >> 4;
    int b = blk & 15;
    int tid = threadIdx.x;
    int g = tid >> 6;          // gate / wave
    int lane = tid & 63;
    int v = lane >> 2;         // k-chunk 0..15 (16 floats each)
    int u = lane & 3;          // row subgroup 0..3

    const float* whh = dir ? whh_b : whh_f;
    float4 w[4][4];            // [row j][k-quad i] -- static indices only
#pragma unroll
    for (int j = 0; j < 4; ++j)
#pragma unroll
        for (int i = 0; i < 4; ++i)
            w[j][i] = *(const float4*)(whh +
                (size_t)(g * 256 + b * 16 + 4 * u + j) * 256 + 16 * v + 4 * i);
#pragma unroll
    for (int j = 0; j < 4; ++j)
#pragma unroll
        for (int i = 0; i < 4; ++i)
            asm volatile("" : "+v"(w[j][i].x), "+v"(w[j][i].y),
                              "+v"(w[j][i].z), "+v"(w[j][i].w));

    const float* xwd = xw + (size_t)dir * S_LEN * 1024;
    float* hsd = hs + (size_t)dir * S_LEN * 256;
    unsigned long long* ringd = ring + dir * 512;   // [slot(2)][dim(256)]

    __shared__ __align__(16) float hbf[320];    // dim d at [(d>>4)*20 + (d&15)]
    __shared__ __align__(16) float zpart[1056]; // [g*264 + v*16 + u*4 + j]
    for (int i = tid; i < 320; i += 256) hbf[i] = 0.f;
    float c = 0.f;                              // wave0 lanes<16
    int crow = (lane >> 4) * 256 + b * 16 + (lane & 15);  // wave0 combine row
    float xw_cur = (g == 0) ? xwd[crow] : 0.f;
    __syncthreads();

    for (int t = 0; t < S_LEN; ++t) {
        // ---- matvec: 4 conflict-free b128 h-reads + 64 static FMAs ----
        const float4* hb4 = (const float4*)hbf + v * 5;   // 20 floats = 5xfloat4
        float4 h0 = hb4[0], h1 = hb4[1], h2 = hb4[2], h3 = hb4[3];
        float s0, s1, s2, s3;
        {
            float4 a0, a1, a2, a3;
            a0.x = w[0][0].x * h0.x; a0.y = w[0][0].y * h0.y;
            a0.z = w[0][0].z * h0.z; a0.w = w[0][0].w * h0.w;
            a1.x = w[1][0].x * h0.x; a1.y = w[1][0].y * h0.y;
            a1.z = w[1][0].z * h0.z; a1.w = w[1][0].w * h0.w;
            a2.x = w[2][0].x * h0.x; a2.y = w[2][0].y * h0.y;
            a2.z = w[2][0].z * h0.z; a2.w = w[2][0].w * h0.w;
            a3.x = w[3][0].x * h0.x; a3.y = w[3][0].y * h0.y;
            a3.z = w[3][0].z * h0.z; a3.w = w[3][0].w * h0.w;

            a0.x = fmaf(w[0][1].x, h1.x, a0.x); a0.y = fmaf(w[0][1].y, h1.y, a0.y);
            a0.z = fmaf(w[0][1].z, h1.z, a0.z); a0.w = fmaf(w[0][1].w, h1.w, a0.w);
            a1.x = fmaf(w[1][1].x, h1.x, a1.x); a1.y = fmaf(w[1][1].y, h1.y, a1.y);
            a1.z = fmaf(w[1][1].z, h1.z, a1.z); a1.w = fmaf(w[1][1].w, h1.w, a1.w);
            a2.x = fmaf(w[2][1].x, h1.x, a2.x); a2.y = fmaf(w[2][1].y, h1.y, a2.y);
            a2.z = fmaf(w[2][1].z, h1.z, a2.z); a2.w = fmaf(w[2][1].w, h1.w, a2.w);
            a3.x = fmaf(w[3][1].x, h1.x, a3.x); a3.y = fmaf(w[3][1].y, h1.y, a3.y);
            a3.z = fmaf(w[3][1].z, h1.z, a3.z); a3.w = fmaf(w[3][1].w, h1.w, a3.w);

            a0.x = fmaf(w[0][2].x, h2.x, a0.x); a0.y = fmaf(w[0][2].y, h2.y, a0.y);
            a0.z = fmaf(w[0][2].z, h2.z, a0.z); a0.w = fmaf(w[0][2].w, h2.w, a0.w);
            a1.x = fmaf(w[1][2].x, h2.x, a1.x); a1.y = fmaf(w[1][2].y, h2.y, a1.y);
            a1.z = fmaf(w[1][2].z, h2.z, a1.z); a1.w = fmaf(w[1][2].w, h2.w, a1.w);
            a2.x = fmaf(w[2][2].x, h2.x, a2.x); a2.y = fmaf(w[2][2].y, h2.y, a2.y);
            a2.z = fmaf(w[2][2].z, h2.z, a2.z); a2.w = fmaf(w[2][2].w, h2.w, a2.w);
            a3.x = fmaf(w[3][2].x, h2.x, a3.x); a3.y = fmaf(w[3][2].y, h2.y, a3.y);
            a3.z = fmaf(w[3][2].z, h2.z, a3.z); a3.w = fmaf(w[3][2].w, h2.w, a3.w);

            a0.x = fmaf(w[0][3].x, h3.x, a0.x); a0.y = fmaf(w[0][3].y, h3.y, a0.y);
            a0.z = fmaf(w[0][3].z, h3.z, a0.z); a0.w = fmaf(w[0][3].w, h3.w, a0.w);
            a1.x = fmaf(w[1][3].x, h3.x, a1.x); a1.y = fmaf(w[1][3].y, h3.y, a1.y);
            a1.z = fmaf(w[1][3].z, h3.z, a1.z); a1.w = fmaf(w[1][3].w, h3.w, a1.w);
            a2.x = fmaf(w[2][3].x, h3.x, a2.x); a2.y = fmaf(w[2][3].y, h3.y, a2.y);
            a2.z = fmaf(w[2][3].z, h3.z, a2.z); a2.w = fmaf(w[2][3].w, h3.w, a2.w);
            a3.x = fmaf(w[3][3].x, h3.x, a3.x); a3.y = fmaf(w[3][3].y, h3.y, a3.y);
            a3.z = fmaf(w[3][3].z, h3.z, a3.z); a3.w = fmaf(w[3][3].w, h3.w, a3.w);

            s0 = (a0.x + a0.y) + (a0.z + a0.w);
            s1 = (a1.x + a1.y) + (a1.z + a1.w);
            s2 = (a2.x + a2.y) + (a2.z + a2.w);
            s3 = (a3.x + a3.y) + (a3.z + a3.w);
        }
        *(float4*)&zpart[g * 264 + v * 16 + u * 4] = make_float4(s0, s1, s2, s3);
        __syncthreads();   // (A) zpart ready

        if (g == 0) {
            int g2 = lane >> 4, s = lane & 15;
            const float* zp = &zpart[g2 * 264 + s];
            float z = xw_cur;
#pragma unroll
            for (int vv = 0; vv < 16; ++vv) z += zp[vv * 16];
            int tn = (t + 1 < S_LEN) ? t + 1 : t;
            float xw_next = xwd[(size_t)tn * 1024 + crow];  // prefetch under poll
            float act = (g2 == 2) ? tanhf(z) : 1.f / (1.f + expf(-z));
            float fg = __shfl(act, (lane & 15) + 16, 64);
            float gg = __shfl(act, (lane & 15) + 32, 64);
            float og = __shfl(act, (lane & 15) + 48, 64);
            unsigned long long* slot = ringd + (size_t)(t & 1) * 256;
            unsigned int want = (unsigned int)(t + 1);
            if (lane < 16) {
                c = fmaf(fg, c, act * gg);     // act == ig in lanes<16
                float h = og * tanhf(c);
                hsd[(size_t)t * 256 + b * 16 + lane] = h;
                unsigned long long pk = ((unsigned long long)want << 32) |
                                        (unsigned long long)__float_as_uint(h);
                __hip_atomic_store(&slot[b * 16 + lane], pk,
                                   __ATOMIC_RELAXED, __HIP_MEMORY_SCOPE_AGENT);
            }
            unsigned long long v0, v1, v2, v3;
            for (;;) {
                v0 = __hip_atomic_load(&slot[lane], __ATOMIC_RELAXED, __HIP_MEMORY_SCOPE_AGENT);
                v1 = __hip_atomic_load(&slot[lane + 64], __ATOMIC_RELAXED, __HIP_MEMORY_SCOPE_AGENT);
                v2 = __hip_atomic_load(&slot[lane + 128], __ATOMIC_RELAXED, __HIP_MEMORY_SCOPE_AGENT);
                v3 = __hip_atomic_load(&slot[lane + 192], __ATOMIC_RELAXED, __HIP_MEMORY_SCOPE_AGENT);
                bool ok = ((unsigned int)(v0 >> 32) == want) &
                          ((unsigned int)(v1 >> 32) == want) &
                          ((unsigned int)(v2 >> 32) == want) &
                          ((unsigned int)(v3 >> 32) == want);
                if (__all(ok)) break;
            }
            int sl = lane & 15, ch = lane >> 4;
            hbf[(ch + 0) * 20 + sl]  = __uint_as_float((unsigned int)v0);
            hbf[(ch + 4) * 20 + sl]  = __uint_as_float((unsigned int)v1);
            hbf[(ch + 8) * 20 + sl]  = __uint_as_float((unsigned int)v2);
            hbf[(ch + 12) * 20 + sl] = __uint_as_float((unsigned int)v3);
            xw_cur = xw_next;
        }
        __syncthreads();   // (C) hbf = h_t for everyone
    }
}

// ---------------- feats = [h_f, h_b] @ W_out^T + b_out ----------------
__global__ __launch_bounds__(64) void feats_k(const float* __restrict__ hs,
                                              const float* __restrict__ wout,
                                              const float* __restrict__ bout,
                                              float* __restrict__ feats) {
    int t = blockIdx.x, tau = blockIdx.y, lane = threadIdx.x;
    const float* hf = hs + (size_t)t * 256;
    const float* hbk = hs + (size_t)S_LEN * 256 + (size_t)(S_LEN - 1 - t) * 256;
    const float* w = wout + (size_t)tau * 512;
    float s = 0.f;
#pragma unroll
    for (int m = 0; m < 4; ++m) s = fmaf(w[lane + 64 * m], hf[lane + 64 * m], s);
#pragma unroll
    for (int m = 0; m < 4; ++m) s = fmaf(w[256 + lane + 64 * m], hbk[lane + 64 * m], s);
#pragma unroll
    for (int off = 32; off > 0; off >>= 1) s += __shfl_down(s, off, 64);
    if (lane == 0) feats[(size_t)t * NTAG + tau] = s + bout[tau];
}

// ---------------- Viterbi (single wave; bp table + path in LDS) ----------------
__global__ __launch_bounds__(64) void viterbi_k(const float* __restrict__ feats,
                                                const float* __restrict__ trans,
                                                float* __restrict__ out) {
    __shared__ float fstage[128 * NTAG];
    __shared__ unsigned char bp[S_LEN * NTAG];
    __shared__ float path[S_LEN];
    __shared__ float fvbuf[NTAG];
    __shared__ float term[NTAG];
    int tid = threadIdx.x;
    float tr[NTAG];
    float trstop = 0.f;
    if (tid < NTAG) {
#pragma unroll
        for (int j = 0; j < NTAG; ++j) tr[j] = trans[tid * NTAG + j];
        trstop = trans[STOP_TAG * NTAG + tid];
    }
    float fv = (tid == START_TAG) ? 0.f : NEGV;
    for (int t0 = 0; t0 < S_LEN; t0 += 128) {
        __syncthreads();
        for (int i = tid; i < 128 * NTAG; i += 64) fstage[i] = feats[(size_t)t0 * NTAG + i];
        __syncthreads();
        for (int tt = 0; tt < 128; ++tt) {
            int t = t0 + tt;
            if (tid < NTAG) fvbuf[tid] = fv;
            __syncthreads();
            if (tid < NTAG) {
                float best = -3.4e38f; int bj = 0;
#pragma unroll
                for (int j = 0; j < NTAG; ++j) {
                    float v = fvbuf[j] + tr[j];
                    if (v > best) { best = v; bj = j; }
                }
                bp[t * NTAG + tid] = (unsigned char)bj;
                fv = best + fstage[tt * NTAG + tid];
            }
            __syncthreads();
        }
    }
    if (tid < NTAG) term[tid] = fv + trstop;
    __syncthreads();
    if (tid == 0) {
        float best = -3.4e38f; int bi = 0;
#pragma unroll
        for (int i = 0; i < NTAG; ++i) {
            float v = term[i];
            if (v > best) { best = v; bi = i; }
        }
        out[0] = best;
        int tag = bi;
        for (int t = S_LEN - 1; t >= 0; --t) {
            path[t] = (float)tag;
            tag = bp[t * NTAG + tag];
        }
    }
    __syncthreads();
    for (int i = tid; i < S_LEN; i += 64) out[1 + i] = path[i];
}

extern "C" void kernel_launch(void* const* d_in, const int* in_sizes, int n_in,
                              void* d_out, int out_size, void* d_ws, size_t ws_size,
                              hipStream_t stream) {
    const int* sent = (const int*)d_in[0];
    const float* emb = (const float*)d_in[1];
    const float* wih_f = (const float*)d_in[2];
    const float* whh_f = (const float*)d_in[3];
    const float* bih_f = (const float*)d_in[4];
    const float* bhh_f = (const float*)d_in[5];
    const float* wih_b = (const float*)d_in[6];
    const float* whh_b = (const float*)d_in[7];
    const float* bih_b = (const float*)d_in[8];
    const float* bhh_b = (const float*)d_in[9];
    const float* wout = (const float*)d_in[10];
    const float* bout = (const float*)d_in[11];
    const float* trans = (const float*)d_in[12];

    float* ws = (float*)d_ws;
    float* xw = ws + XW_OFF;
    float* hs = ws + HS_OFF;
    float* wT = ws + WT_OFF;
    float* fe = ws + FE_OFF;
    unsigned long long* ring = (unsigned long long*)(ws + RING_OFF);

    hipLaunchKernelGGL(transpose_wih, dim3(8, 32, 2), dim3(32, 32), 0, stream,
                       wih_f, wih_b, wT);
    hipLaunchKernelGGL(xw_gemm, dim3(S_LEN / 16, 2), dim3(256), 0, stream,
                       sent, emb, wT, bih_f, bhh_f, bih_b, bhh_b, xw);
    hipLaunchKernelGGL(lstm_rec, dim3(32), dim3(256), 0, stream,
                       whh_f, whh_b, xw, hs, ring);
    hipLaunchKernelGGL(feats_k, dim3(S_LEN, NTAG), dim3(64), 0, stream,
                       hs, wout, bout, fe);
    hipLaunchKernelGGL(viterbi_k, dim3(1), dim3(64), 0, stream,
                       fe, trans, (float*)d_out);
}